// Round 10
// baseline (483.964 us; speedup 1.0000x reference)
//
#include <hip/hip_runtime.h>

// QTT 3D sampling, round 19: M=4/wave, 4-way K-split, 2048 blocks.
//   Occupancy play: acc[4] (16 VGPR) + 8-row B ping-pong (32) ~= 58 VGPR
//   -> <=64 band -> 8 waves/SIMD eligible; 2048 blocks = 8 blocks/CU =
//   32 waves/CU (2x r18). LDS ~8.3 KB. launch_bounds(256,6) as spill hedge
//   (budget 85 >> need; never forces below requirement).
//
//   out[i] = P3[a_i] · U[d4_i*512 + q_i]   (round-11 reassociation)
//   K0 (32 blocks):  C4t[d4][s5][k] = C4[k][d4][s5]   (transpose)
//   K1 (2048 blocks):
//     bx 0-1023    P3 block (d0, half, d2, d3): 4 rows d1 = half*4 + r,
//                  A from C0/C1/C2, B = C3[d3] rows (stride 2048).
//     bx 1024-2047 U block (d4, half, qt): 4 rows q = qt*8 + half*4 + r,
//                  A = T rows in-situ from C5/C6/C7, B = C4t[d4] (stride 256).
//     GEMM: wave wv streams B rows k in [64wv,64wv+64) global->VGPR
//     (2-deep ping-pong, disjoint across waves), acc[4]; then 2-phase
//     4-way cross-wave reduce through 8KB LDS (waves 0,1 store).
//   K2 (n/8 blocks): out[i] = dot256(P3[a_i], U[...]), 2 samples/wave.
// Core shapes: (r_l, 8, r_{l+1}), ranks 1,8,64,256,256,256,64,8,1.
// C_l[k][d][s] at C_l[k*8*r_out + d*r_out + s].

typedef unsigned int u32;

__device__ __forceinline__ void fma4(float4& c, float a, const float4& b) {
    c.x = fmaf(a, b.x, c.x); c.y = fmaf(a, b.y, c.y);
    c.z = fmaf(a, b.z, c.z); c.w = fmaf(a, b.w, c.w);
}
__device__ __forceinline__ int digit_of(int x, int y, int z, int sh) {
    return 4*((x>>sh)&1) + 2*((y>>sh)&1) + ((z>>sh)&1);
}

// ---------------- K0: C4 transpose ------------------------------------------
__global__ __launch_bounds__(256, 4) void prep_kernel(
    const float* __restrict__ C4, float* __restrict__ C4t)
{
    const int t = threadIdx.x;
    const int cb = blockIdx.x;
    const int d4 = cb >> 2, s5q = cb & 3;
#pragma unroll 8
    for (int j = 0; j < 64; ++j) {
        const int s5 = s5q*64 + j;
        C4t[(size_t)d4*65536 + (size_t)s5*256 + t] =
            C4[(size_t)t*2048 + d4*256 + s5];
    }
}

__device__ __forceinline__ void comp4(
    const float (*As)[260], int kk,
    const float4& b0, const float4& b1, const float4& b2, const float4& b3,
    float4* acc)
{
#pragma unroll
    for (int r = 0; r < 4; ++r) {
        const float4 a = *(const float4*)&As[r][kk];
        fma4(acc[r], a.x, b0); fma4(acc[r], a.y, b1);
        fma4(acc[r], a.z, b2); fma4(acc[r], a.w, b3);
    }
}

// Per-wave K-chunk GEMM: 4 rows x 256 cols, this wave's K in
// [kbase, kbase+64). B row k at Bg + k*rowStride (cols contiguous),
// streamed global->VGPR with 2-deep ping-pong. A broadcast from LDS.
__device__ __forceinline__ void kgemm4(
    const float* __restrict__ Bg, int rowStride,
    const float (*As)[260], int kbase, int ln, float4* acc)
{
    const float* gp = Bg + (size_t)kbase * rowStride + (size_t)ln * 4;
    float4 bA0 = *(const float4*)(gp + (size_t)0*rowStride);
    float4 bA1 = *(const float4*)(gp + (size_t)1*rowStride);
    float4 bA2 = *(const float4*)(gp + (size_t)2*rowStride);
    float4 bA3 = *(const float4*)(gp + (size_t)3*rowStride);
    float4 bB0 = *(const float4*)(gp + (size_t)4*rowStride);
    float4 bB1 = *(const float4*)(gp + (size_t)5*rowStride);
    float4 bB2 = *(const float4*)(gp + (size_t)6*rowStride);
    float4 bB3 = *(const float4*)(gp + (size_t)7*rowStride);

#pragma unroll 1
    for (int s = 0; s < 8; ++s) {
        const int k0 = s * 8;
        comp4(As, kbase + k0, bA0, bA1, bA2, bA3, acc);
        if (s < 7) {
            bA0 = *(const float4*)(gp + (size_t)(k0+ 8)*rowStride);
            bA1 = *(const float4*)(gp + (size_t)(k0+ 9)*rowStride);
            bA2 = *(const float4*)(gp + (size_t)(k0+10)*rowStride);
            bA3 = *(const float4*)(gp + (size_t)(k0+11)*rowStride);
        }
        comp4(As, kbase + k0 + 4, bB0, bB1, bB2, bB3, acc);
        if (s < 7) {
            bB0 = *(const float4*)(gp + (size_t)(k0+12)*rowStride);
            bB1 = *(const float4*)(gp + (size_t)(k0+13)*rowStride);
            bB2 = *(const float4*)(gp + (size_t)(k0+14)*rowStride);
            bB3 = *(const float4*)(gp + (size_t)(k0+15)*rowStride);
        }
    }
}

// ---------------- K1: dense P3 table + dense U table (in-situ T) -------------
__global__ __launch_bounds__(256, 6) void tables_kernel(
    const float* __restrict__ C0, const float* __restrict__ C1,
    const float* __restrict__ C2, const float* __restrict__ C3,
    const float* __restrict__ C4t, const float* __restrict__ C5,
    const float* __restrict__ C6, const float* __restrict__ C7,
    float* __restrict__ P3, float* __restrict__ U)
{
    __shared__ __align__(16) union {
        struct { float small[4][64]; float As[4][260]; } g;   // 5.2 KB
        float red[4][2][256];                                 // 8 KB
    } u;
    const int t = threadIdx.x;
    const int ln = t & 63, wv = t >> 6;
    const int bx = blockIdx.x;

    float4 acc[4];
#pragma unroll
    for (int r = 0; r < 4; ++r) acc[r] = make_float4(0,0,0,0);

    const float* Bg;
    int rowStride, rowBase, rowStep;
    float* outP;

    if (bx < 1024) {
        // ---- P3 block: (d0, half, d2, d3); 4 rows d1 = half*4 + r ----
        const int d3 = bx & 7, d2 = (bx >> 3) & 7;
        const int half = (bx >> 6) & 1, d0 = bx >> 7;

        // v64[r][c] = sum_r8 C0[d0,r8] * C1[r8, half*4+r, c]  (1/thread)
        {
            const int r = t >> 6, c = t & 63;
            float a = 0.f;
#pragma unroll
            for (int r8 = 0; r8 < 8; ++r8)
                a = fmaf(C0[d0*8 + r8],
                         C1[r8*512 + (half*4 + r)*64 + c], a);
            u.g.small[r][c] = a;
        }
        __syncthreads();

        // As[wv][k] = sum_j v64[wv][j] * C2[j, d2, k]  (wave wv owns row wv)
        {
            float4 a0 = make_float4(0,0,0,0);
            const float* c2base = C2 + d2*256 + ln*4;
#pragma unroll 8
            for (int j = 0; j < 64; ++j) {
                const float4 c2 = *(const float4*)(c2base + (size_t)j*2048);
                fma4(a0, u.g.small[wv][j], c2);
            }
            *(float4*)&u.g.As[wv][ln*4] = a0;
        }
        __syncthreads();

        Bg = C3 + d3*256; rowStride = 2048;
        rowBase = d0*512 + (half*4)*64 + d2*8 + d3;
        rowStep = 64;                        // row(i) = base + i*64 (d1)
        outP = P3;
    } else {
        // ---- U block: (d4, half, qt); 4 rows q = qt*8 + half*4 + r ----
        const int ub = bx - 1024;
        const int qt = ub & 63, half = (ub >> 6) & 1, d4 = ub >> 7;
        const int d5 = qt >> 3, d6 = qt & 7;

        // small[r][s6] = sum_jj C6[s6, d6, jj] * C7[jj, half*4+r]  (1/thread)
        {
            const int r = t >> 6, s6 = t & 63;
            float a = 0.f;
#pragma unroll
            for (int jj = 0; jj < 8; ++jj)
                a = fmaf(C6[s6*64 + d6*8 + jj], C7[jj*8 + half*4 + r], a);
            u.g.small[r][s6] = a;
        }
        __syncthreads();

        // As[r][s5=t] = T[q(r)][t] = sum_s6 C5[t, d5, s6] * small[r][s6]
        {
            float accT[4];
#pragma unroll
            for (int r = 0; r < 4; ++r) accT[r] = 0.f;
#pragma unroll
            for (int j4 = 0; j4 < 16; ++j4) {
                const float4 c5 = *(const float4*)(C5 + (size_t)t*512
                                                   + d5*64 + j4*4);
#pragma unroll
                for (int r = 0; r < 4; ++r) {
                    const float4 s6v = *(const float4*)&u.g.small[r][j4*4];
                    accT[r] = fmaf(c5.x, s6v.x, accT[r]);
                    accT[r] = fmaf(c5.y, s6v.y, accT[r]);
                    accT[r] = fmaf(c5.z, s6v.z, accT[r]);
                    accT[r] = fmaf(c5.w, s6v.w, accT[r]);
                }
            }
#pragma unroll
            for (int r = 0; r < 4; ++r) u.g.As[r][t] = accT[r];
        }
        __syncthreads();

        Bg = C4t + (size_t)d4*65536; rowStride = 256;
        rowBase = d4*512 + qt*8 + half*4;
        rowStep = 1;                         // row(i) = base + i
        outP = U;
    }

    // per-wave K-chunk GEMM (barrier-free)
    kgemm4(Bg, rowStride, u.g.As, wv*64, ln, acc);

    __syncthreads();   // all waves done reading As before red overlays it

    // 2-phase 4-way cross-wave reduce; waves 0,1 finalize rows ph*2+{0,1}
#pragma unroll
    for (int ph = 0; ph < 2; ++ph) {
        *(float4*)&u.red[wv][0][ln*4] = acc[ph*2 + 0];
        *(float4*)&u.red[wv][1][ln*4] = acc[ph*2 + 1];
        __syncthreads();
        if (wv < 2) {
            float4 v        = *(const float4*)&u.red[0][wv][ln*4];
            const float4 p1 = *(const float4*)&u.red[1][wv][ln*4];
            const float4 p2 = *(const float4*)&u.red[2][wv][ln*4];
            const float4 p3 = *(const float4*)&u.red[3][wv][ln*4];
            v.x += p1.x + p2.x + p3.x; v.y += p1.y + p2.y + p3.y;
            v.z += p1.z + p2.z + p3.z; v.w += p1.w + p2.w + p3.w;
            const int r = ph*2 + wv;
            *(float4*)(outP + (size_t)(rowBase + rowStep*r)*256 + ln*4) = v;
        }
        __syncthreads();
    }
}

// ---------------- K2: per-sample dot(P3 row, U row), 2 samples/wave ----------
__global__ __launch_bounds__(256) void final_kernel(
    const float* __restrict__ P3, const float* __restrict__ U,
    const int* __restrict__ coords, int n, float* __restrict__ out)
{
    const int ln = threadIdx.x & 63, wv = threadIdx.x >> 6;
    const int s0 = blockIdx.x * 8 + wv * 2;

    float p[2] = {0.f, 0.f};
    int valid[2];
#pragma unroll
    for (int i = 0; i < 2; ++i) {
        const int s = s0 + i;
        valid[i] = (s < n);
        if (valid[i]) {
            const int x = coords[3*s], y = coords[3*s+1], z = coords[3*s+2];
            const int a  = digit_of(x,y,z,7)*512 + digit_of(x,y,z,6)*64
                         + digit_of(x,y,z,5)*8  + digit_of(x,y,z,4);
            const int d4 = digit_of(x,y,z,3);
            const int q  = digit_of(x,y,z,2)*64 + digit_of(x,y,z,1)*8
                         + digit_of(x,y,z,0);
            const float4 p4 = *(const float4*)(P3 + (size_t)a*256 + ln*4);
            const float4 u4 = *(const float4*)(U + (size_t)(d4*512 + q)*256 + ln*4);
            p[i] = fmaf(p4.x, u4.x, fmaf(p4.y, u4.y,
                   fmaf(p4.z, u4.z, p4.w * u4.w)));
        }
    }
#pragma unroll
    for (int m = 1; m <= 32; m <<= 1) {
        p[0] += __shfl_xor(p[0], m);
        p[1] += __shfl_xor(p[1], m);
    }
    if (ln == 0) {
        if (valid[0]) out[s0]     = p[0];
        if (valid[1]) out[s0 + 1] = p[1];
    }
}

extern "C" void kernel_launch(void* const* d_in, const int* in_sizes, int n_in,
                              void* d_out, int out_size, void* d_ws, size_t ws_size,
                              hipStream_t stream) {
    const float* C0 = (const float*)d_in[0];
    const float* C1 = (const float*)d_in[1];
    const float* C2 = (const float*)d_in[2];
    const float* C3 = (const float*)d_in[3];
    const float* C4 = (const float*)d_in[4];
    const float* C5 = (const float*)d_in[5];
    const float* C6 = (const float*)d_in[6];
    const float* C7 = (const float*)d_in[7];
    const int* coords = (const int*)d_in[8];
    float* out = (float*)d_out;

    const int n = in_sizes[8] / 3;

    // workspace (~10.5 MB)
    float* P3  = (float*)d_ws;                 // 4096*256
    float* U   = P3 + 4096*256;                // 4096*256
    float* C4t = U  + 4096*256;                // 8*256*256

    prep_kernel<<<32, 256, 0, stream>>>(C4, C4t);
    tables_kernel<<<2048, 256, 0, stream>>>(
        C0, C1, C2, C3, C4t, C5, C6, C7, P3, U);
    final_kernel<<<(n + 7) / 8, 256, 0, stream>>>(P3, U, coords, n, out);
}

// Round 11
// 108.844 us; speedup vs baseline: 4.4464x; 4.4464x over previous
//
#include <hip/hip_runtime.h>

// QTT 3D sampling, round 20: r18 (best, 111.1us) + compile-time B stride.
//   ONLY change vs r18: kgemm8 templated on ROWSTRIDE so the U path's 1KB
//   row stride folds into global_load immediate offsets (0..7KB fit the
//   13-bit signed imm) and the P3 path's 8KB stride is a constant fold.
//   launch_bounds stays (256,2): (256,4)->64VGPR and (256,6)->40VGPR both
//   spilled catastrophically (r17: 105MB, r19: 1.28GB scratch writes).
//
//   out[i] = P3[a_i] · U[d4_i*512 + q_i]   (round-11 reassociation)
//   K0 (32 blocks):  C4t[d4][s5][k] = C4[k][d4][s5]   (transpose)
//   K1 (1024 blocks = 4/CU):
//     bx 0-511   P3 block (d0,d2,d3): 8 rows (d1), A from C0/C1/C2, B=C3[d3]
//     bx 512-1023 U block (d4,qt): 8 rows q=qt*8+r, A = T rows in-situ
//                from C5/C6/C7, B = C4t[d4] (stride 256).
//     GEMM: wave wv streams B rows k in [64wv,64wv+64) global->VGPR
//     (2-deep ping-pong, disjoint across waves), then 2-phase 4-way
//     cross-wave reduce through 16KB LDS.
//   K2 (n/8 blocks): out[i] = dot256(P3[a_i], U[...]), 2 samples/wave.
// Core shapes: (r_l, 8, r_{l+1}), ranks 1,8,64,256,256,256,64,8,1.
// C_l[k][d][s] at C_l[k*8*r_out + d*r_out + s].

typedef unsigned int u32;

__device__ __forceinline__ void fma4(float4& c, float a, const float4& b) {
    c.x = fmaf(a, b.x, c.x); c.y = fmaf(a, b.y, c.y);
    c.z = fmaf(a, b.z, c.z); c.w = fmaf(a, b.w, c.w);
}
__device__ __forceinline__ int digit_of(int x, int y, int z, int sh) {
    return 4*((x>>sh)&1) + 2*((y>>sh)&1) + ((z>>sh)&1);
}

// ---------------- K0: C4 transpose ------------------------------------------
__global__ __launch_bounds__(256, 4) void prep_kernel(
    const float* __restrict__ C4, float* __restrict__ C4t)
{
    const int t = threadIdx.x;
    const int cb = blockIdx.x;
    const int d4 = cb >> 2, s5q = cb & 3;
#pragma unroll 8
    for (int j = 0; j < 64; ++j) {
        const int s5 = s5q*64 + j;
        C4t[(size_t)d4*65536 + (size_t)s5*256 + t] =
            C4[(size_t)t*2048 + d4*256 + s5];
    }
}

__device__ __forceinline__ void comp8(
    const float (*As)[260], int kk,
    const float4& b0, const float4& b1, const float4& b2, const float4& b3,
    float4* acc)
{
#pragma unroll
    for (int r = 0; r < 8; ++r) {
        const float4 a = *(const float4*)&As[r][kk];
        fma4(acc[r], a.x, b0); fma4(acc[r], a.y, b1);
        fma4(acc[r], a.z, b2); fma4(acc[r], a.w, b3);
    }
}

// Per-wave K-chunk GEMM: 8 rows x 256 cols, this wave's K in
// [kbase, kbase+64). B row k at Bg + k*ROWSTRIDE (cols contiguous),
// streamed global->VGPR with 2-deep ping-pong. A broadcast from LDS.
// ROWSTRIDE is compile-time so row offsets fold to constants/immediates.
template<int ROWSTRIDE>
__device__ __forceinline__ void kgemm8(
    const float* __restrict__ Bg,
    const float (*As)[260], int kbase, int ln, float4* acc)
{
    const float* gp = Bg + (size_t)kbase * ROWSTRIDE + (size_t)ln * 4;
    float4 bA0 = *(const float4*)(gp + (size_t)0*ROWSTRIDE);
    float4 bA1 = *(const float4*)(gp + (size_t)1*ROWSTRIDE);
    float4 bA2 = *(const float4*)(gp + (size_t)2*ROWSTRIDE);
    float4 bA3 = *(const float4*)(gp + (size_t)3*ROWSTRIDE);
    float4 bB0 = *(const float4*)(gp + (size_t)4*ROWSTRIDE);
    float4 bB1 = *(const float4*)(gp + (size_t)5*ROWSTRIDE);
    float4 bB2 = *(const float4*)(gp + (size_t)6*ROWSTRIDE);
    float4 bB3 = *(const float4*)(gp + (size_t)7*ROWSTRIDE);

#pragma unroll 1
    for (int s = 0; s < 8; ++s) {
        const int k0 = s * 8;
        comp8(As, kbase + k0, bA0, bA1, bA2, bA3, acc);
        if (s < 7) {
            bA0 = *(const float4*)(gp + (size_t)(k0+ 8)*ROWSTRIDE);
            bA1 = *(const float4*)(gp + (size_t)(k0+ 9)*ROWSTRIDE);
            bA2 = *(const float4*)(gp + (size_t)(k0+10)*ROWSTRIDE);
            bA3 = *(const float4*)(gp + (size_t)(k0+11)*ROWSTRIDE);
        }
        comp8(As, kbase + k0 + 4, bB0, bB1, bB2, bB3, acc);
        if (s < 7) {
            bB0 = *(const float4*)(gp + (size_t)(k0+12)*ROWSTRIDE);
            bB1 = *(const float4*)(gp + (size_t)(k0+13)*ROWSTRIDE);
            bB2 = *(const float4*)(gp + (size_t)(k0+14)*ROWSTRIDE);
            bB3 = *(const float4*)(gp + (size_t)(k0+15)*ROWSTRIDE);
        }
    }
}

// ---------------- K1: dense P3 table + dense U table (in-situ T) -------------
__global__ __launch_bounds__(256, 2) void tables_kernel(
    const float* __restrict__ C0, const float* __restrict__ C1,
    const float* __restrict__ C2, const float* __restrict__ C3,
    const float* __restrict__ C4t, const float* __restrict__ C5,
    const float* __restrict__ C6, const float* __restrict__ C7,
    float* __restrict__ P3, float* __restrict__ U)
{
    __shared__ __align__(16) union {
        struct { float small[8][64]; float As[8][260]; } g;   // 10.1 KB
        float red[4][4][256];                                 // 16 KB
    } u;
    const int t = threadIdx.x;
    const int ln = t & 63, wv = t >> 6;
    const int bx = blockIdx.x;

    float4 acc[8];
#pragma unroll
    for (int r = 0; r < 8; ++r) acc[r] = make_float4(0,0,0,0);

    int rowBase, rowStep;
    float* outP;

    if (bx < 512) {
        // ---- P3 block: (d0, d2, d3); 8 rows = d1 ----
        const int d3 = bx & 7, d2 = (bx >> 3) & 7, d0 = bx >> 6;

        // v64[d1][c] = sum_r C0[d0,r] * C1[r, d1, c]   (2 entries/thread)
#pragma unroll
        for (int j = 0; j < 2; ++j) {
            const int idx = t + 256*j, d1 = idx >> 6, c = idx & 63;
            float a = 0.f;
#pragma unroll
            for (int r8 = 0; r8 < 8; ++r8)
                a = fmaf(C0[d0*8 + r8], C1[r8*512 + d1*64 + c], a);
            u.g.small[d1][c] = a;
        }
        __syncthreads();

        // As[d1][k] = sum_j v64[d1][j] * C2[j, d2, k]; wave wv: d1=wv*2+{0,1}
        {
            float4 a0 = make_float4(0,0,0,0), a1 = make_float4(0,0,0,0);
            const float* c2base = C2 + d2*256 + ln*4;
#pragma unroll 8
            for (int j = 0; j < 64; ++j) {
                const float4 c2 = *(const float4*)(c2base + (size_t)j*2048);
                fma4(a0, u.g.small[wv*2 + 0][j], c2);
                fma4(a1, u.g.small[wv*2 + 1][j], c2);
            }
            *(float4*)&u.g.As[wv*2 + 0][ln*4] = a0;
            *(float4*)&u.g.As[wv*2 + 1][ln*4] = a1;
        }
        __syncthreads();

        // per-wave K-chunk GEMM (barrier-free), B = C3[d3], stride 2048
        kgemm8<2048>(C3 + d3*256, u.g.As, wv*64, ln, acc);

        rowBase = d0*512 + d2*8 + d3; rowStep = 64;  // row = base + d1*64
        outP = P3;
    } else {
        // ---- U block: (d4, qtile8); 8 rows q = qt*8 + r (r = d7) ----
        const int ub = bx - 512;
        const int qt = ub & 63, d4 = ub >> 6;
        const int d5 = qt >> 3, d6 = qt & 7;

        // small[r][s6] = sum_jj C6[s6, d6, jj] * C7[jj, r]  (2 entries/thread)
#pragma unroll
        for (int j = 0; j < 2; ++j) {
            const int idx = t + 256*j, r = idx >> 6, s6 = idx & 63;
            float a = 0.f;
#pragma unroll
            for (int jj = 0; jj < 8; ++jj)
                a = fmaf(C6[s6*64 + d6*8 + jj], C7[jj*8 + r], a);
            u.g.small[r][s6] = a;
        }
        __syncthreads();

        // As[r][s5=t] = T[qt*8+r][t] = sum_s6 C5[t, d5, s6] * small[r][s6]
        {
            float accT[8];
#pragma unroll
            for (int r = 0; r < 8; ++r) accT[r] = 0.f;
#pragma unroll
            for (int j4 = 0; j4 < 16; ++j4) {
                const float4 c5 = *(const float4*)(C5 + (size_t)t*512
                                                   + d5*64 + j4*4);
#pragma unroll
                for (int r = 0; r < 8; ++r) {
                    const float4 s6v = *(const float4*)&u.g.small[r][j4*4];
                    accT[r] = fmaf(c5.x, s6v.x, accT[r]);
                    accT[r] = fmaf(c5.y, s6v.y, accT[r]);
                    accT[r] = fmaf(c5.z, s6v.z, accT[r]);
                    accT[r] = fmaf(c5.w, s6v.w, accT[r]);
                }
            }
#pragma unroll
            for (int r = 0; r < 8; ++r) u.g.As[r][t] = accT[r];
        }
        __syncthreads();

        // per-wave K-chunk GEMM (barrier-free), B = C4t[d4], stride 256
        kgemm8<256>(C4t + (size_t)d4*65536, u.g.As, wv*64, ln, acc);

        rowBase = d4*512 + qt*8; rowStep = 1;        // row = base + r
        outP = U;
    }

    __syncthreads();   // all waves done reading As before red overlays it

    // 2-phase 4-way cross-wave reduce; wave wv handles row ph*4+wv
#pragma unroll
    for (int ph = 0; ph < 2; ++ph) {
#pragma unroll
        for (int i = 0; i < 4; ++i)
            *(float4*)&u.red[wv][i][ln*4] = acc[ph*4 + i];
        __syncthreads();
        {
            float4 v        = *(const float4*)&u.red[0][wv][ln*4];
            const float4 p1 = *(const float4*)&u.red[1][wv][ln*4];
            const float4 p2 = *(const float4*)&u.red[2][wv][ln*4];
            const float4 p3 = *(const float4*)&u.red[3][wv][ln*4];
            v.x += p1.x + p2.x + p3.x; v.y += p1.y + p2.y + p3.y;
            v.z += p1.z + p2.z + p3.z; v.w += p1.w + p2.w + p3.w;
            const int r = ph*4 + wv;
            *(float4*)(outP + (size_t)(rowBase + rowStep*r)*256 + ln*4) = v;
        }
        __syncthreads();
    }
}

// ---------------- K2: per-sample dot(P3 row, U row), 2 samples/wave ----------
__global__ __launch_bounds__(256) void final_kernel(
    const float* __restrict__ P3, const float* __restrict__ U,
    const int* __restrict__ coords, int n, float* __restrict__ out)
{
    const int ln = threadIdx.x & 63, wv = threadIdx.x >> 6;
    const int s0 = blockIdx.x * 8 + wv * 2;

    float p[2] = {0.f, 0.f};
    int valid[2];
#pragma unroll
    for (int i = 0; i < 2; ++i) {
        const int s = s0 + i;
        valid[i] = (s < n);
        if (valid[i]) {
            const int x = coords[3*s], y = coords[3*s+1], z = coords[3*s+2];
            const int a  = digit_of(x,y,z,7)*512 + digit_of(x,y,z,6)*64
                         + digit_of(x,y,z,5)*8  + digit_of(x,y,z,4);
            const int d4 = digit_of(x,y,z,3);
            const int q  = digit_of(x,y,z,2)*64 + digit_of(x,y,z,1)*8
                         + digit_of(x,y,z,0);
            const float4 p4 = *(const float4*)(P3 + (size_t)a*256 + ln*4);
            const float4 u4 = *(const float4*)(U + (size_t)(d4*512 + q)*256 + ln*4);
            p[i] = fmaf(p4.x, u4.x, fmaf(p4.y, u4.y,
                   fmaf(p4.z, u4.z, p4.w * u4.w)));
        }
    }
#pragma unroll
    for (int m = 1; m <= 32; m <<= 1) {
        p[0] += __shfl_xor(p[0], m);
        p[1] += __shfl_xor(p[1], m);
    }
    if (ln == 0) {
        if (valid[0]) out[s0]     = p[0];
        if (valid[1]) out[s0 + 1] = p[1];
    }
}

extern "C" void kernel_launch(void* const* d_in, const int* in_sizes, int n_in,
                              void* d_out, int out_size, void* d_ws, size_t ws_size,
                              hipStream_t stream) {
    const float* C0 = (const float*)d_in[0];
    const float* C1 = (const float*)d_in[1];
    const float* C2 = (const float*)d_in[2];
    const float* C3 = (const float*)d_in[3];
    const float* C4 = (const float*)d_in[4];
    const float* C5 = (const float*)d_in[5];
    const float* C6 = (const float*)d_in[6];
    const float* C7 = (const float*)d_in[7];
    const int* coords = (const int*)d_in[8];
    float* out = (float*)d_out;

    const int n = in_sizes[8] / 3;

    // workspace (~10.5 MB)
    float* P3  = (float*)d_ws;                 // 4096*256
    float* U   = P3 + 4096*256;                // 4096*256
    float* C4t = U  + 4096*256;                // 8*256*256

    prep_kernel<<<32, 256, 0, stream>>>(C4, C4t);
    tables_kernel<<<1024, 256, 0, stream>>>(
        C0, C1, C2, C3, C4t, C5, C6, C7, P3, U);
    final_kernel<<<(n + 7) / 8, 256, 0, stream>>>(P3, U, coords, n, out);
}

// Round 12
// 106.949 us; speedup vs baseline: 4.5252x; 1.0177x over previous
//
#include <hip/hip_runtime.h>

// QTT 3D sampling, round 21: r20 (best, 108.8us) + K2 MLP + faster K0.
//   K1 byte-identical to r20. Changes:
//   - K2: 4 samples/wave (256 blocks), 8 float4 loads in flight per wave
//     (2x MLP), 4 interleaved shfl-reduce chains.
//   - K0: 64 blocks (half the serial per-block loop).
//   launch_bounds on K1 stays (256,2): (256,4)->64VGPR and (256,6)->40VGPR
//   both spilled catastrophically (r17: 105MB, r19: 1.28GB scratch).
//
//   out[i] = P3[a_i] · U[d4_i*512 + q_i]   (round-11 reassociation)
//   K0 (64 blocks):  C4t[d4][s5][k] = C4[k][d4][s5]   (transpose)
//   K1 (1024 blocks = 4/CU):
//     bx 0-511   P3 block (d0,d2,d3): 8 rows (d1), A from C0/C1/C2, B=C3[d3]
//     bx 512-1023 U block (d4,qt): 8 rows q=qt*8+r, A = T rows in-situ
//                from C5/C6/C7, B = C4t[d4] (stride 256).
//     GEMM: wave wv streams B rows k in [64wv,64wv+64) global->VGPR
//     (2-deep ping-pong, disjoint across waves), then 2-phase 4-way
//     cross-wave reduce through 16KB LDS.
//   K2 (n/16 blocks): out[i] = dot256(P3[a_i], U[...]), 4 samples/wave.
// Core shapes: (r_l, 8, r_{l+1}), ranks 1,8,64,256,256,256,64,8,1.
// C_l[k][d][s] at C_l[k*8*r_out + d*r_out + s].

typedef unsigned int u32;

__device__ __forceinline__ void fma4(float4& c, float a, const float4& b) {
    c.x = fmaf(a, b.x, c.x); c.y = fmaf(a, b.y, c.y);
    c.z = fmaf(a, b.z, c.z); c.w = fmaf(a, b.w, c.w);
}
__device__ __forceinline__ int digit_of(int x, int y, int z, int sh) {
    return 4*((x>>sh)&1) + 2*((y>>sh)&1) + ((z>>sh)&1);
}

// ---------------- K0: C4 transpose ------------------------------------------
__global__ __launch_bounds__(256, 4) void prep_kernel(
    const float* __restrict__ C4, float* __restrict__ C4t)
{
    const int t = threadIdx.x;
    const int cb = blockIdx.x;
    const int d4 = cb >> 3, s5o = cb & 7;
#pragma unroll 8
    for (int j = 0; j < 32; ++j) {
        const int s5 = s5o*32 + j;
        C4t[(size_t)d4*65536 + (size_t)s5*256 + t] =
            C4[(size_t)t*2048 + d4*256 + s5];
    }
}

__device__ __forceinline__ void comp8(
    const float (*As)[260], int kk,
    const float4& b0, const float4& b1, const float4& b2, const float4& b3,
    float4* acc)
{
#pragma unroll
    for (int r = 0; r < 8; ++r) {
        const float4 a = *(const float4*)&As[r][kk];
        fma4(acc[r], a.x, b0); fma4(acc[r], a.y, b1);
        fma4(acc[r], a.z, b2); fma4(acc[r], a.w, b3);
    }
}

// Per-wave K-chunk GEMM: 8 rows x 256 cols, this wave's K in
// [kbase, kbase+64). B row k at Bg + k*ROWSTRIDE (cols contiguous),
// streamed global->VGPR with 2-deep ping-pong. A broadcast from LDS.
// ROWSTRIDE is compile-time so row offsets fold to constants/immediates.
template<int ROWSTRIDE>
__device__ __forceinline__ void kgemm8(
    const float* __restrict__ Bg,
    const float (*As)[260], int kbase, int ln, float4* acc)
{
    const float* gp = Bg + (size_t)kbase * ROWSTRIDE + (size_t)ln * 4;
    float4 bA0 = *(const float4*)(gp + (size_t)0*ROWSTRIDE);
    float4 bA1 = *(const float4*)(gp + (size_t)1*ROWSTRIDE);
    float4 bA2 = *(const float4*)(gp + (size_t)2*ROWSTRIDE);
    float4 bA3 = *(const float4*)(gp + (size_t)3*ROWSTRIDE);
    float4 bB0 = *(const float4*)(gp + (size_t)4*ROWSTRIDE);
    float4 bB1 = *(const float4*)(gp + (size_t)5*ROWSTRIDE);
    float4 bB2 = *(const float4*)(gp + (size_t)6*ROWSTRIDE);
    float4 bB3 = *(const float4*)(gp + (size_t)7*ROWSTRIDE);

#pragma unroll 1
    for (int s = 0; s < 8; ++s) {
        const int k0 = s * 8;
        comp8(As, kbase + k0, bA0, bA1, bA2, bA3, acc);
        if (s < 7) {
            bA0 = *(const float4*)(gp + (size_t)(k0+ 8)*ROWSTRIDE);
            bA1 = *(const float4*)(gp + (size_t)(k0+ 9)*ROWSTRIDE);
            bA2 = *(const float4*)(gp + (size_t)(k0+10)*ROWSTRIDE);
            bA3 = *(const float4*)(gp + (size_t)(k0+11)*ROWSTRIDE);
        }
        comp8(As, kbase + k0 + 4, bB0, bB1, bB2, bB3, acc);
        if (s < 7) {
            bB0 = *(const float4*)(gp + (size_t)(k0+12)*ROWSTRIDE);
            bB1 = *(const float4*)(gp + (size_t)(k0+13)*ROWSTRIDE);
            bB2 = *(const float4*)(gp + (size_t)(k0+14)*ROWSTRIDE);
            bB3 = *(const float4*)(gp + (size_t)(k0+15)*ROWSTRIDE);
        }
    }
}

// ---------------- K1: dense P3 table + dense U table (in-situ T) -------------
__global__ __launch_bounds__(256, 2) void tables_kernel(
    const float* __restrict__ C0, const float* __restrict__ C1,
    const float* __restrict__ C2, const float* __restrict__ C3,
    const float* __restrict__ C4t, const float* __restrict__ C5,
    const float* __restrict__ C6, const float* __restrict__ C7,
    float* __restrict__ P3, float* __restrict__ U)
{
    __shared__ __align__(16) union {
        struct { float small[8][64]; float As[8][260]; } g;   // 10.1 KB
        float red[4][4][256];                                 // 16 KB
    } u;
    const int t = threadIdx.x;
    const int ln = t & 63, wv = t >> 6;
    const int bx = blockIdx.x;

    float4 acc[8];
#pragma unroll
    for (int r = 0; r < 8; ++r) acc[r] = make_float4(0,0,0,0);

    int rowBase, rowStep;
    float* outP;

    if (bx < 512) {
        // ---- P3 block: (d0, d2, d3); 8 rows = d1 ----
        const int d3 = bx & 7, d2 = (bx >> 3) & 7, d0 = bx >> 6;

        // v64[d1][c] = sum_r C0[d0,r] * C1[r, d1, c]   (2 entries/thread)
#pragma unroll
        for (int j = 0; j < 2; ++j) {
            const int idx = t + 256*j, d1 = idx >> 6, c = idx & 63;
            float a = 0.f;
#pragma unroll
            for (int r8 = 0; r8 < 8; ++r8)
                a = fmaf(C0[d0*8 + r8], C1[r8*512 + d1*64 + c], a);
            u.g.small[d1][c] = a;
        }
        __syncthreads();

        // As[d1][k] = sum_j v64[d1][j] * C2[j, d2, k]; wave wv: d1=wv*2+{0,1}
        {
            float4 a0 = make_float4(0,0,0,0), a1 = make_float4(0,0,0,0);
            const float* c2base = C2 + d2*256 + ln*4;
#pragma unroll 8
            for (int j = 0; j < 64; ++j) {
                const float4 c2 = *(const float4*)(c2base + (size_t)j*2048);
                fma4(a0, u.g.small[wv*2 + 0][j], c2);
                fma4(a1, u.g.small[wv*2 + 1][j], c2);
            }
            *(float4*)&u.g.As[wv*2 + 0][ln*4] = a0;
            *(float4*)&u.g.As[wv*2 + 1][ln*4] = a1;
        }
        __syncthreads();

        // per-wave K-chunk GEMM (barrier-free), B = C3[d3], stride 2048
        kgemm8<2048>(C3 + d3*256, u.g.As, wv*64, ln, acc);

        rowBase = d0*512 + d2*8 + d3; rowStep = 64;  // row = base + d1*64
        outP = P3;
    } else {
        // ---- U block: (d4, qtile8); 8 rows q = qt*8 + r (r = d7) ----
        const int ub = bx - 512;
        const int qt = ub & 63, d4 = ub >> 6;
        const int d5 = qt >> 3, d6 = qt & 7;

        // small[r][s6] = sum_jj C6[s6, d6, jj] * C7[jj, r]  (2 entries/thread)
#pragma unroll
        for (int j = 0; j < 2; ++j) {
            const int idx = t + 256*j, r = idx >> 6, s6 = idx & 63;
            float a = 0.f;
#pragma unroll
            for (int jj = 0; jj < 8; ++jj)
                a = fmaf(C6[s6*64 + d6*8 + jj], C7[jj*8 + r], a);
            u.g.small[r][s6] = a;
        }
        __syncthreads();

        // As[r][s5=t] = T[qt*8+r][t] = sum_s6 C5[t, d5, s6] * small[r][s6]
        {
            float accT[8];
#pragma unroll
            for (int r = 0; r < 8; ++r) accT[r] = 0.f;
#pragma unroll
            for (int j4 = 0; j4 < 16; ++j4) {
                const float4 c5 = *(const float4*)(C5 + (size_t)t*512
                                                   + d5*64 + j4*4);
#pragma unroll
                for (int r = 0; r < 8; ++r) {
                    const float4 s6v = *(const float4*)&u.g.small[r][j4*4];
                    accT[r] = fmaf(c5.x, s6v.x, accT[r]);
                    accT[r] = fmaf(c5.y, s6v.y, accT[r]);
                    accT[r] = fmaf(c5.z, s6v.z, accT[r]);
                    accT[r] = fmaf(c5.w, s6v.w, accT[r]);
                }
            }
#pragma unroll
            for (int r = 0; r < 8; ++r) u.g.As[r][t] = accT[r];
        }
        __syncthreads();

        // per-wave K-chunk GEMM (barrier-free), B = C4t[d4], stride 256
        kgemm8<256>(C4t + (size_t)d4*65536, u.g.As, wv*64, ln, acc);

        rowBase = d4*512 + qt*8; rowStep = 1;        // row = base + r
        outP = U;
    }

    __syncthreads();   // all waves done reading As before red overlays it

    // 2-phase 4-way cross-wave reduce; wave wv handles row ph*4+wv
#pragma unroll
    for (int ph = 0; ph < 2; ++ph) {
#pragma unroll
        for (int i = 0; i < 4; ++i)
            *(float4*)&u.red[wv][i][ln*4] = acc[ph*4 + i];
        __syncthreads();
        {
            float4 v        = *(const float4*)&u.red[0][wv][ln*4];
            const float4 p1 = *(const float4*)&u.red[1][wv][ln*4];
            const float4 p2 = *(const float4*)&u.red[2][wv][ln*4];
            const float4 p3 = *(const float4*)&u.red[3][wv][ln*4];
            v.x += p1.x + p2.x + p3.x; v.y += p1.y + p2.y + p3.y;
            v.z += p1.z + p2.z + p3.z; v.w += p1.w + p2.w + p3.w;
            const int r = ph*4 + wv;
            *(float4*)(outP + (size_t)(rowBase + rowStep*r)*256 + ln*4) = v;
        }
        __syncthreads();
    }
}

// ---------------- K2: per-sample dot(P3 row, U row), 4 samples/wave ----------
__global__ __launch_bounds__(256) void final_kernel(
    const float* __restrict__ P3, const float* __restrict__ U,
    const int* __restrict__ coords, int n, float* __restrict__ out)
{
    const int ln = threadIdx.x & 63, wv = threadIdx.x >> 6;
    const int s0 = blockIdx.x * 16 + wv * 4;

    float p[4] = {0.f, 0.f, 0.f, 0.f};
    int valid[4];
#pragma unroll
    for (int i = 0; i < 4; ++i) {
        const int s = s0 + i;
        valid[i] = (s < n);
        if (valid[i]) {
            const int x = coords[3*s], y = coords[3*s+1], z = coords[3*s+2];
            const int a  = digit_of(x,y,z,7)*512 + digit_of(x,y,z,6)*64
                         + digit_of(x,y,z,5)*8  + digit_of(x,y,z,4);
            const int d4 = digit_of(x,y,z,3);
            const int q  = digit_of(x,y,z,2)*64 + digit_of(x,y,z,1)*8
                         + digit_of(x,y,z,0);
            const float4 p4 = *(const float4*)(P3 + (size_t)a*256 + ln*4);
            const float4 u4 = *(const float4*)(U + (size_t)(d4*512 + q)*256 + ln*4);
            p[i] = fmaf(p4.x, u4.x, fmaf(p4.y, u4.y,
                   fmaf(p4.z, u4.z, p4.w * u4.w)));
        }
    }
#pragma unroll
    for (int m = 1; m <= 32; m <<= 1) {
        p[0] += __shfl_xor(p[0], m);
        p[1] += __shfl_xor(p[1], m);
        p[2] += __shfl_xor(p[2], m);
        p[3] += __shfl_xor(p[3], m);
    }
    if (ln == 0) {
#pragma unroll
        for (int i = 0; i < 4; ++i)
            if (valid[i]) out[s0 + i] = p[i];
    }
}

extern "C" void kernel_launch(void* const* d_in, const int* in_sizes, int n_in,
                              void* d_out, int out_size, void* d_ws, size_t ws_size,
                              hipStream_t stream) {
    const float* C0 = (const float*)d_in[0];
    const float* C1 = (const float*)d_in[1];
    const float* C2 = (const float*)d_in[2];
    const float* C3 = (const float*)d_in[3];
    const float* C4 = (const float*)d_in[4];
    const float* C5 = (const float*)d_in[5];
    const float* C6 = (const float*)d_in[6];
    const float* C7 = (const float*)d_in[7];
    const int* coords = (const int*)d_in[8];
    float* out = (float*)d_out;

    const int n = in_sizes[8] / 3;

    // workspace (~10.5 MB)
    float* P3  = (float*)d_ws;                 // 4096*256
    float* U   = P3 + 4096*256;                // 4096*256
    float* C4t = U  + 4096*256;                // 8*256*256

    prep_kernel<<<64, 256, 0, stream>>>(C4, C4t);
    tables_kernel<<<1024, 256, 0, stream>>>(
        C0, C1, C2, C3, C4t, C5, C6, C7, P3, U);
    final_kernel<<<(n + 15) / 16, 256, 0, stream>>>(P3, U, coords, n, out);
}